// Round 1
// baseline (198.917 us; speedup 1.0000x reference)
//
#include <hip/hip_runtime.h>
#include <hip/hip_bf16.h>
#include <hip/hip_fp16.h>

typedef _Float16 half8 __attribute__((ext_vector_type(8)));
typedef _Float16 half4 __attribute__((ext_vector_type(4)));
typedef float floatx4 __attribute__((ext_vector_type(4)));

#define BATCH   4096
#define NIN     1024
#define NODES   4095
#define NPAD    4096
#define NOUT    1024
#define NLEAF   4096

__device__ __forceinline__ void gload_lds16(const void* g, void* l) {
    __builtin_amdgcn_global_load_lds(
        (const __attribute__((address_space(1))) void*)g,
        (__attribute__((address_space(3))) void*)l, 16, 0, 0);
}

// ---------- convert f32 -> f16, zero-padding past nsrc ----------
__global__ void k_f32_to_f16_pad(const float* __restrict__ src,
                                 _Float16* __restrict__ dst, int n, int nsrc) {
    int i = (blockIdx.x * blockDim.x + threadIdx.x) * 4;
    if (i >= n) return;
    float4 v;
    if (i < nsrc) v = *(const float4*)(src + i);
    else          v = make_float4(0.f, 0.f, 0.f, 0.f);
    half4 h;
    h.x = (_Float16)v.x; h.y = (_Float16)v.y;
    h.z = (_Float16)v.z; h.w = (_Float16)v.w;
    *(half4*)(dst + i) = h;
}

// ---------- transpose leaf [NLEAF][NOUT] f32 -> leafT [NOUT][NLEAF] f16 ----------
__global__ void k_transpose_f16(const float* __restrict__ src,
                                _Float16* __restrict__ dst) {
    __shared__ _Float16 t[32][33];
    int l0 = blockIdx.x * 32, o0 = blockIdx.y * 32;
    int tx = threadIdx.x & 31, ty = threadIdx.x >> 5;  // 32 x 8
#pragma unroll
    for (int i = 0; i < 4; i++) {
        int l = l0 + ty + i * 8;
        t[ty + i * 8][tx] = (_Float16)src[(size_t)l * NOUT + o0 + tx];
    }
    __syncthreads();
#pragma unroll
    for (int i = 0; i < 4; i++) {
        int o = o0 + ty + i * 8;
        dst[(size_t)o * NLEAF + l0 + tx] = t[tx][ty + i * 8];
    }
}

// ---------- 128x128 gemm_bt: C = A(MxK) * B(NxK)^T ----------
// EPILOGUE==1: C fp16 = sigmoid(acc + bias[col]) (gate GEMM)
// EPILOGUE==0: C f32 = acc (leaf GEMM)
template <int EPILOGUE>
__launch_bounds__(256)
__global__ void gemm_bt(const _Float16* __restrict__ A,
                        const _Float16* __restrict__ Bm,
                        const float* __restrict__ bias,
                        void* __restrict__ C,
                        int M, int N, int K, int ldc) {
    __shared__ __align__(16) _Float16 As[128 * 32];
    __shared__ __align__(16) _Float16 Bs[128 * 32];
    const int tid  = threadIdx.x;
    const int lane = tid & 63;
    const int wave = tid >> 6;
    const int wr = wave >> 1, wc = wave & 1;
    const int m0 = blockIdx.y * 128;
    const int n0 = blockIdx.x * 128;

    floatx4 acc[4][4] = {};

    // staging: 512 chunks of 16B per matrix per K-tile; thread covers chunk tid and tid+256
    const int rA0 = tid >> 2;            // row 0..63 (second issue: +64)
    const int kel = (tid & 3) * 8;       // k element offset within 32-wide tile

    const _Float16* Ag  = A  + (size_t)(m0 + rA0) * K + kel;
    const _Float16* Ag2 = A  + (size_t)(m0 + rA0 + 64) * K + kel;
    const _Float16* Bg  = Bm + (size_t)(n0 + rA0) * K + kel;
    const _Float16* Bg2 = Bm + (size_t)(n0 + rA0 + 64) * K + kel;

    _Float16* AsW  = As + tid * 8;
    _Float16* AsW2 = As + 2048 + tid * 8;
    _Float16* BsW  = Bs + tid * 8;
    _Float16* BsW2 = Bs + 2048 + tid * 8;

    const int arow = wr * 64 + (lane & 15);
    const int brow = wc * 64 + (lane & 15);
    const int akel = (lane >> 4) * 8;

    for (int kt = 0; kt < K; kt += 32) {
        gload_lds16(Ag + kt,  AsW);
        gload_lds16(Ag2 + kt, AsW2);
        gload_lds16(Bg + kt,  BsW);
        gload_lds16(Bg2 + kt, BsW2);
        __syncthreads();  // drains vmcnt(0) before any wave reads LDS
        half8 af[4], bf[4];
#pragma unroll
        for (int i = 0; i < 4; i++)
            af[i] = *(const half8*)(As + (arow + i * 16) * 32 + akel);
#pragma unroll
        for (int j = 0; j < 4; j++)
            bf[j] = *(const half8*)(Bs + (brow + j * 16) * 32 + akel);
#pragma unroll
        for (int i = 0; i < 4; i++)
#pragma unroll
            for (int j = 0; j < 4; j++)
                acc[i][j] = __builtin_amdgcn_mfma_f32_16x16x32_f16(
                    af[i], bf[j], acc[i][j], 0, 0, 0);
        __syncthreads();  // all waves done reading before next stage overwrites
    }

    const int crow0 = m0 + wr * 64 + (lane >> 4) * 4;
    const int ccol0 = n0 + wc * 64 + (lane & 15);
#pragma unroll
    for (int i = 0; i < 4; i++) {
#pragma unroll
        for (int j = 0; j < 4; j++) {
            int col = ccol0 + j * 16;
#pragma unroll
            for (int r = 0; r < 4; r++) {
                int row = crow0 + i * 16 + r;
                float v = acc[i][j][r];
                if (EPILOGUE == 1) {
                    float bb = (col < NODES) ? bias[col] : 0.f;
                    float z = v + bb;
                    float gg = 1.f / (1.f + __expf(-z));
                    ((_Float16*)C)[(size_t)row * ldc + col] = (_Float16)gg;
                } else {
                    ((float*)C)[(size_t)row * ldc + col] = v;
                }
            }
        }
    }
}

// ---------- probs: per batch row, hierarchical tree-product expansion ----------
__global__ void k_probs(const _Float16* __restrict__ g,
                        _Float16* __restrict__ probs) {
    __shared__ float gs[NPAD];
    const int b = blockIdx.x;
    const _Float16* grow = g + (size_t)b * NPAD;
#pragma unroll
    for (int it = 0; it < 2; it++) {
        int i = threadIdx.x + it * 256;   // i in [0,512): 8 halves each
        half8 v = *(const half8*)(grow + i * 8);
#pragma unroll
        for (int j = 0; j < 8; j++) gs[i * 8 + j] = (float)v[j];
    }
    __syncthreads();
    const int t = threadIdx.x;  // subtree over leaves [t*16, t*16+16)
    // prefix product over depths 0..7
    float p = 1.f;
#pragma unroll
    for (int d = 0; d < 8; d++) {
        int node = (1 << d) - 1 + (t >> (8 - d));
        float gg = gs[node];
        int bit = (t >> (7 - d)) & 1;
        p *= bit ? gg : (1.f - gg);
    }
    // depth 8..11 within subtree
    float p9[2], p10[4], p11[8], p12[16];
    {
        float gg = gs[255 + t];
        p9[0] = p * (1.f - gg); p9[1] = p * gg;
    }
#pragma unroll
    for (int i = 0; i < 2; i++) {
        float gg = gs[511 + 2 * t + i];
        p10[2 * i] = p9[i] * (1.f - gg); p10[2 * i + 1] = p9[i] * gg;
    }
#pragma unroll
    for (int i = 0; i < 4; i++) {
        float gg = gs[1023 + 4 * t + i];
        p11[2 * i] = p10[i] * (1.f - gg); p11[2 * i + 1] = p10[i] * gg;
    }
#pragma unroll
    for (int i = 0; i < 8; i++) {
        float gg = gs[2047 + 8 * t + i];
        p12[2 * i] = p11[i] * (1.f - gg); p12[2 * i + 1] = p11[i] * gg;
    }
    half8 o0, o1;
#pragma unroll
    for (int j = 0; j < 8; j++) { o0[j] = (_Float16)p12[j]; o1[j] = (_Float16)p12[8 + j]; }
    _Float16* pr = probs + (size_t)b * NLEAF + t * 16;
    *(half8*)(pr) = o0;
    *(half8*)(pr + 8) = o1;
}

extern "C" void kernel_launch(void* const* d_in, const int* in_sizes, int n_in,
                              void* d_out, int out_size, void* d_ws, size_t ws_size,
                              hipStream_t stream) {
    (void)in_sizes; (void)n_in; (void)out_size; (void)ws_size;
    const float* x    = (const float*)d_in[0];
    const float* W    = (const float*)d_in[1];
    const float* bias = (const float*)d_in[2];
    const float* leaf = (const float*)d_in[3];
    float* out = (float*)d_out;

    _Float16* xh    = (_Float16*)d_ws;                       // 8 MB
    _Float16* Wh    = xh + (size_t)BATCH * NIN;              // 8 MB
    _Float16* leafT = Wh + (size_t)NPAD * NIN;               // 8 MB
    _Float16* g     = leafT + (size_t)NOUT * NLEAF;          // 32 MB
    _Float16* probs = g + (size_t)BATCH * NPAD;              // 32 MB

    k_f32_to_f16_pad<<<(BATCH * NIN / 4 + 255) / 256, 256, 0, stream>>>(
        x, xh, BATCH * NIN, BATCH * NIN);
    k_f32_to_f16_pad<<<(NPAD * NIN / 4 + 255) / 256, 256, 0, stream>>>(
        W, Wh, NPAD * NIN, NODES * NIN);
    k_transpose_f16<<<dim3(NLEAF / 32, NOUT / 32), 256, 0, stream>>>(leaf, leafT);

    gemm_bt<1><<<dim3(NPAD / 128, BATCH / 128), 256, 0, stream>>>(
        xh, Wh, bias, (void*)g, BATCH, NPAD, NIN, NPAD);

    k_probs<<<BATCH, 256, 0, stream>>>(g, probs);

    gemm_bt<0><<<dim3(NOUT / 128, BATCH / 128), 256, 0, stream>>>(
        probs, leafT, nullptr, (void*)out, BATCH, NOUT, NLEAF, NOUT);
}

// Round 2
// 170.793 us; speedup vs baseline: 1.1647x; 1.1647x over previous
//
#include <hip/hip_runtime.h>
#include <hip/hip_bf16.h>
#include <hip/hip_fp16.h>

typedef _Float16 half8 __attribute__((ext_vector_type(8)));
typedef _Float16 half4 __attribute__((ext_vector_type(4)));
typedef float floatx4 __attribute__((ext_vector_type(4)));

#define BATCH   4096
#define NIN     1024
#define NODES   4095
#define NPAD    4096
#define NOUT    1024
#define NLEAF   4096

__device__ __forceinline__ void gload_lds16(const void* g, void* l) {
    __builtin_amdgcn_global_load_lds(
        (const __attribute__((address_space(1))) void*)g,
        (__attribute__((address_space(3))) void*)l, 16, 0, 0);
}

// ---------- convert f32 -> f16, zero-padding past nsrc ----------
__global__ void k_f32_to_f16_pad(const float* __restrict__ src,
                                 _Float16* __restrict__ dst, int n, int nsrc) {
    int i = (blockIdx.x * blockDim.x + threadIdx.x) * 4;
    if (i >= n) return;
    float4 v;
    if (i < nsrc) v = *(const float4*)(src + i);
    else          v = make_float4(0.f, 0.f, 0.f, 0.f);
    half4 h;
    h.x = (_Float16)v.x; h.y = (_Float16)v.y;
    h.z = (_Float16)v.z; h.w = (_Float16)v.w;
    *(half4*)(dst + i) = h;
}

// ---------- transpose leaf [NLEAF][NOUT] f32 -> leafT [NOUT][NLEAF] f16 ----------
__global__ void k_transpose_f16(const float* __restrict__ src,
                                _Float16* __restrict__ dst) {
    __shared__ _Float16 t[32][33];
    int l0 = blockIdx.x * 32, o0 = blockIdx.y * 32;
    int tx = threadIdx.x & 31, ty = threadIdx.x >> 5;  // 32 x 8
#pragma unroll
    for (int i = 0; i < 4; i++) {
        int l = l0 + ty + i * 8;
        t[ty + i * 8][tx] = (_Float16)src[(size_t)l * NOUT + o0 + tx];
    }
    __syncthreads();
#pragma unroll
    for (int i = 0; i < 4; i++) {
        int o = o0 + ty + i * 8;
        dst[(size_t)o * NLEAF + l0 + tx] = t[tx][ty + i * 8];
    }
}

// ---------- 128x128 gemm_bt: C = A(MxK) * B(NxK)^T ----------
// 2-phase double-buffered LDS pipeline (stage k+1 before compute k, ONE barrier/K-step).
// LDS chunk swizzle (both sides): chunk stored at pos = c ^ ((row>>1)&3).
//   - write side: LDS dest stays linear (global_load_lds requirement, m104);
//     the GLOBAL source chunk is pre-swizzled instead (rule 21).
//   - read side: same XOR applied when computing ds_read address.
//   Result: 8 distinct 16B slots per 8 consecutive rows -> 2-way conflict (free).
// EPILOGUE==1: C fp16 = sigmoid(acc + bias[col]) (gate GEMM)
// EPILOGUE==0: C f32 = acc (leaf GEMM)
template <int EPILOGUE>
__launch_bounds__(256)
__global__ void gemm_bt(const _Float16* __restrict__ A,
                        const _Float16* __restrict__ Bm,
                        const float* __restrict__ bias,
                        void* __restrict__ C,
                        int M, int N, int K, int ldc) {
    __shared__ __align__(16) _Float16 As[2][128 * 32];
    __shared__ __align__(16) _Float16 Bs[2][128 * 32];
    const int tid  = threadIdx.x;
    const int lane = tid & 63;
    const int wave = tid >> 6;
    const int wr = wave >> 1, wc = wave & 1;
    const int m0 = blockIdx.y * 128;
    const int n0 = blockIdx.x * 128;

    floatx4 acc[4][4] = {};

    // staging: thread tid covers LDS 16B slot tid (row=tid>>2, pos=tid&3) and slot tid+256.
    // That slot must hold global chunk c = pos ^ ((row>>1)&3)  ->  pre-swizzle the source.
    const int rA0 = tid >> 2;                                // local row 0..63 (2nd issue: +64)
    const int cg  = ((tid & 3) ^ ((tid >> 3) & 3)) * 8;      // swizzled source chunk (halves)

    const _Float16* Ag  = A  + (size_t)(m0 + rA0) * K + cg;
    const _Float16* Ag2 = Ag + (size_t)64 * K;
    const _Float16* Bg  = Bm + (size_t)(n0 + rA0) * K + cg;
    const _Float16* Bg2 = Bg + (size_t)64 * K;

    _Float16* AsW[2] = { &As[0][tid * 8], &As[1][tid * 8] };
    _Float16* BsW[2] = { &Bs[0][tid * 8], &Bs[1][tid * 8] };

    const int arow = wr * 64 + (lane & 15);
    const int brow = wc * 64 + (lane & 15);
    const int csel = lane >> 4;            // which global chunk this lane's fragment wants

    // prologue: stage tile 0 into buf 0
    gload_lds16(Ag,  AsW[0]);
    gload_lds16(Ag2, AsW[0] + 2048);
    gload_lds16(Bg,  BsW[0]);
    gload_lds16(Bg2, BsW[0] + 2048);
    __syncthreads();

    int buf = 0;
    for (int kt = 0; kt < K; kt += 32) {
        if (kt + 32 < K) {  // stage next tile into the other buffer
            gload_lds16(Ag  + kt + 32, AsW[buf ^ 1]);
            gload_lds16(Ag2 + kt + 32, AsW[buf ^ 1] + 2048);
            gload_lds16(Bg  + kt + 32, BsW[buf ^ 1]);
            gload_lds16(Bg2 + kt + 32, BsW[buf ^ 1] + 2048);
        }
        half8 af[4], bf[4];
#pragma unroll
        for (int i = 0; i < 4; i++) {
            int row = arow + i * 16;
            int pos = (csel ^ ((row >> 1) & 3)) * 8;
            af[i] = *(const half8*)(&As[buf][row * 32 + pos]);
        }
#pragma unroll
        for (int j = 0; j < 4; j++) {
            int row = brow + j * 16;
            int pos = (csel ^ ((row >> 1) & 3)) * 8;
            bf[j] = *(const half8*)(&Bs[buf][row * 32 + pos]);
        }
#pragma unroll
        for (int i = 0; i < 4; i++)
#pragma unroll
            for (int j = 0; j < 4; j++)
                acc[i][j] = __builtin_amdgcn_mfma_f32_16x16x32_f16(
                    af[i], bf[j], acc[i][j], 0, 0, 0);
        __syncthreads();  // drains next-tile stage (vmcnt) + this tile's ds_reads (lgkm)
        buf ^= 1;
    }

    const int crow0 = m0 + wr * 64 + (lane >> 4) * 4;
    const int ccol0 = n0 + wc * 64 + (lane & 15);
#pragma unroll
    for (int i = 0; i < 4; i++) {
#pragma unroll
        for (int j = 0; j < 4; j++) {
            int col = ccol0 + j * 16;
#pragma unroll
            for (int r = 0; r < 4; r++) {
                int row = crow0 + i * 16 + r;
                float v = acc[i][j][r];
                if (EPILOGUE == 1) {
                    float bb = (col < NODES) ? bias[col] : 0.f;
                    float z = v + bb;
                    float gg = 1.f / (1.f + __expf(-z));
                    ((_Float16*)C)[(size_t)row * ldc + col] = (_Float16)gg;
                } else {
                    ((float*)C)[(size_t)row * ldc + col] = v;
                }
            }
        }
    }
}

// ---------- probs: per batch row, hierarchical tree-product expansion ----------
__global__ void k_probs(const _Float16* __restrict__ g,
                        _Float16* __restrict__ probs) {
    __shared__ float gs[NPAD];
    const int b = blockIdx.x;
    const _Float16* grow = g + (size_t)b * NPAD;
#pragma unroll
    for (int it = 0; it < 2; it++) {
        int i = threadIdx.x + it * 256;   // i in [0,512): 8 halves each
        half8 v = *(const half8*)(grow + i * 8);
#pragma unroll
        for (int j = 0; j < 8; j++) gs[i * 8 + j] = (float)v[j];
    }
    __syncthreads();
    const int t = threadIdx.x;  // subtree over leaves [t*16, t*16+16)
    float p = 1.f;
#pragma unroll
    for (int d = 0; d < 8; d++) {
        int node = (1 << d) - 1 + (t >> (8 - d));
        float gg = gs[node];
        int bit = (t >> (7 - d)) & 1;
        p *= bit ? gg : (1.f - gg);
    }
    float p9[2], p10[4], p11[8], p12[16];
    {
        float gg = gs[255 + t];
        p9[0] = p * (1.f - gg); p9[1] = p * gg;
    }
#pragma unroll
    for (int i = 0; i < 2; i++) {
        float gg = gs[511 + 2 * t + i];
        p10[2 * i] = p9[i] * (1.f - gg); p10[2 * i + 1] = p9[i] * gg;
    }
#pragma unroll
    for (int i = 0; i < 4; i++) {
        float gg = gs[1023 + 4 * t + i];
        p11[2 * i] = p10[i] * (1.f - gg); p11[2 * i + 1] = p10[i] * gg;
    }
#pragma unroll
    for (int i = 0; i < 8; i++) {
        float gg = gs[2047 + 8 * t + i];
        p12[2 * i] = p11[i] * (1.f - gg); p12[2 * i + 1] = p11[i] * gg;
    }
    half8 o0, o1;
#pragma unroll
    for (int j = 0; j < 8; j++) { o0[j] = (_Float16)p12[j]; o1[j] = (_Float16)p12[8 + j]; }
    _Float16* pr = probs + (size_t)b * NLEAF + t * 16;
    *(half8*)(pr) = o0;
    *(half8*)(pr + 8) = o1;
}

extern "C" void kernel_launch(void* const* d_in, const int* in_sizes, int n_in,
                              void* d_out, int out_size, void* d_ws, size_t ws_size,
                              hipStream_t stream) {
    (void)in_sizes; (void)n_in; (void)out_size; (void)ws_size;
    const float* x    = (const float*)d_in[0];
    const float* W    = (const float*)d_in[1];
    const float* bias = (const float*)d_in[2];
    const float* leaf = (const float*)d_in[3];
    float* out = (float*)d_out;

    _Float16* xh    = (_Float16*)d_ws;                       // 8 MB
    _Float16* Wh    = xh + (size_t)BATCH * NIN;              // 8 MB
    _Float16* leafT = Wh + (size_t)NPAD * NIN;               // 8 MB
    _Float16* g     = leafT + (size_t)NOUT * NLEAF;          // 32 MB
    _Float16* probs = g + (size_t)BATCH * NPAD;              // 32 MB

    k_f32_to_f16_pad<<<(BATCH * NIN / 4 + 255) / 256, 256, 0, stream>>>(
        x, xh, BATCH * NIN, BATCH * NIN);
    k_f32_to_f16_pad<<<(NPAD * NIN / 4 + 255) / 256, 256, 0, stream>>>(
        W, Wh, NPAD * NIN, NODES * NIN);
    k_transpose_f16<<<dim3(NLEAF / 32, NOUT / 32), 256, 0, stream>>>(leaf, leafT);

    gemm_bt<1><<<dim3(NPAD / 128, BATCH / 128), 256, 0, stream>>>(
        xh, Wh, bias, (void*)g, BATCH, NPAD, NIN, NPAD);

    k_probs<<<BATCH, 256, 0, stream>>>(g, probs);

    gemm_bt<0><<<dim3(NOUT / 128, BATCH / 128), 256, 0, stream>>>(
        probs, leafT, nullptr, (void*)out, BATCH, NOUT, NLEAF, NOUT);
}